// Round 10
// baseline (121.378 us; speedup 1.0000x reference)
//
#include <hip/hip_runtime.h>
#include <hip/hip_bf16.h>

// Output[b,0,i] = S[b] for all i, where
//   S[b] = sum_j (row[b,j] + b_row) * (col[b,j] + b_col)
//   col[b,i] = sum_j x[b,i,j] * w_col[j]   (weighted row-dot)
//   row[b,j] = sum_i x[b,i,j] * w_row[i]   (weighted column-sum)
//
// R10 = R9 streaming (depth-2 NT pipeline, uncapped) + fused finalize via
// producer-consumer flags WITHOUT __threadfence (R4's mistake: per-block
// agent acq_rel fence = buffer_wbl2 L2 drains x2048 = catastrophic).
// Here: partials written with __hip_atomic_store(RELAXED, AGENT) -> sc0 sc1
// write-through stores (no dirty L2), __syncthreads drains vmcnt, relaxed
// device-scope atomicAdd arrival counter; ONLY the 128 last-arriving blocks
// execute an acquire-only fence (buffer_inv, no writeback) and finalize.

#define K 1024
#define NB 128

typedef float f32x4 __attribute__((ext_vector_type(4)));

__global__ __launch_bounds__(256) void
fused_kernel(const float* __restrict__ x,
             const float* __restrict__ w_col,
             const float* __restrict__ w_row,
             const float* __restrict__ b_col_p,
             const float* __restrict__ b_row_p,
             float* __restrict__ out,
             float* __restrict__ col_ws,     // [NB][K]
             float* __restrict__ rowpart,    // [NB*16][K]
             int* __restrict__ counters)     // [NB], pre-zeroed by memset
{
    const int bid  = blockIdx.x;
    const int b    = bid >> 4;
    const int rb   = bid & 15;
    const int row0 = rb * 64;
    const int tid  = threadIdx.x;
    const int wave = tid >> 6;
    const int lane = tid & 63;

    const float* xb = x + (size_t)b * K * K;

    // Wave-uniform row base in SGPR so w_row[] reads scalarize to s_load.
    const int rbu = __builtin_amdgcn_readfirstlane(row0 + wave * 16);

    // Register-cache this lane's w_col fragment (reused by all 16 rows)
    f32x4 wc[4];
#pragma unroll
    for (int jt = 0; jt < 4; ++jt)
        wc[jt] = *reinterpret_cast<const f32x4*>(w_col + jt * 256 + lane * 4);

    // Per-lane column partials for row[b,j] (this wave's 16 rows)
    f32x4 p[4];
#pragma unroll
    for (int jt = 0; jt < 4; ++jt) p[jt] = (f32x4){0.f, 0.f, 0.f, 0.f};

    float cacc[16];

    // ---- depth-2 software-pipelined NT streaming loop (as R9) ----
    f32x4 buf[2][4];
    {
        const float* xr0 = xb + (size_t)rbu * K + lane * 4;
        const float* xr1 = xb + (size_t)(rbu + 1) * K + lane * 4;
#pragma unroll
        for (int jt = 0; jt < 4; ++jt)
            buf[0][jt] = __builtin_nontemporal_load(
                reinterpret_cast<const f32x4*>(xr0 + jt * 256));
#pragma unroll
        for (int jt = 0; jt < 4; ++jt)
            buf[1][jt] = __builtin_nontemporal_load(
                reinterpret_cast<const f32x4*>(xr1 + jt * 256));
    }

#pragma unroll
    for (int k = 0; k < 16; ++k) {
        f32x4 n0, n1, n2, n3;
        if (k < 14) {   // issue row k+2's loads before consuming row k
            const float* xn = xb + (size_t)(rbu + k + 2) * K + lane * 4;
            n0 = __builtin_nontemporal_load(reinterpret_cast<const f32x4*>(xn +   0));
            n1 = __builtin_nontemporal_load(reinterpret_cast<const f32x4*>(xn + 256));
            n2 = __builtin_nontemporal_load(reinterpret_cast<const f32x4*>(xn + 512));
            n3 = __builtin_nontemporal_load(reinterpret_cast<const f32x4*>(xn + 768));
        }
        const float wr = w_row[rbu + k];            // s_load, wave-uniform
        f32x4 a0 = buf[k & 1][0], a1 = buf[k & 1][1];
        f32x4 a2 = buf[k & 1][2], a3 = buf[k & 1][3];
        f32x4 c4;
        c4  = a0 * wc[0];
        c4 += a1 * wc[1];
        c4 += a2 * wc[2];
        c4 += a3 * wc[3];
        p[0] += a0 * wr;
        p[1] += a1 * wr;
        p[2] += a2 * wr;
        p[3] += a3 * wr;
        cacc[k] = (c4.x + c4.y) + (c4.z + c4.w);
        if (k < 14) {
            buf[k & 1][0] = n0; buf[k & 1][1] = n1;
            buf[k & 1][2] = n2; buf[k & 1][3] = n3;
        }
    }

    // Multiplexed butterfly: 16 row-dots reduced across 64 lanes.
#pragma unroll
    for (int lvl = 0; lvl < 4; ++lvl) {
        const int s = 1 << lvl;
        const int n = 16 >> (lvl + 1);
#pragma unroll
        for (int m = 0; m < n; ++m) {
            float a  = cacc[2 * m]     + __shfl_xor(cacc[2 * m],     s);
            float bb = cacc[2 * m + 1] + __shfl_xor(cacc[2 * m + 1], s);
            cacc[m] = (lane & s) ? bb : a;
        }
    }
    float r = cacc[0];
    r += __shfl_xor(r, 16);
    r += __shfl_xor(r, 32);
    if (lane < 16)   // coherent write-through store (sc0 sc1), no dirty L2
        __hip_atomic_store(&col_ws[b * K + rbu + lane], r,
                           __ATOMIC_RELAXED, __HIP_MEMORY_SCOPE_AGENT);

    // Combine the 4 waves' column partials in LDS
    __shared__ float rp[4][K];   // 16 KiB
#pragma unroll
    for (int jt = 0; jt < 4; ++jt)
        *reinterpret_cast<f32x4*>(&rp[wave][jt * 256 + lane * 4]) = p[jt];
    __syncthreads();

    const int j0 = tid * 4;
    {
        f32x4 s0 = *reinterpret_cast<const f32x4*>(&rp[0][j0]);
        f32x4 s1 = *reinterpret_cast<const f32x4*>(&rp[1][j0]);
        f32x4 s2 = *reinterpret_cast<const f32x4*>(&rp[2][j0]);
        f32x4 s3 = *reinterpret_cast<const f32x4*>(&rp[3][j0]);
        f32x4 s = (s0 + s1) + (s2 + s3);
        float* dst = &rowpart[(size_t)bid * K + j0];
        __hip_atomic_store(dst + 0, s.x, __ATOMIC_RELAXED, __HIP_MEMORY_SCOPE_AGENT);
        __hip_atomic_store(dst + 1, s.y, __ATOMIC_RELAXED, __HIP_MEMORY_SCOPE_AGENT);
        __hip_atomic_store(dst + 2, s.z, __ATOMIC_RELAXED, __HIP_MEMORY_SCOPE_AGENT);
        __hip_atomic_store(dst + 3, s.w, __ATOMIC_RELAXED, __HIP_MEMORY_SCOPE_AGENT);
    }

    // Drain all partial stores (syncthreads emits s_waitcnt vmcnt(0) per wave
    // before s_barrier), then announce arrival with a relaxed device atomic.
    __syncthreads();
    __shared__ int sprev;
    if (tid == 0)
        sprev = __hip_atomic_fetch_add(&counters[b], 1,
                                       __ATOMIC_RELAXED, __HIP_MEMORY_SCOPE_AGENT);
    __syncthreads();
    if (sprev != 15) return;

    // Only 128 blocks reach here: acquire-only fence (buffer_inv, no wbl2)
    // orders the partial reads after the counter observation.
    __builtin_amdgcn_fence(__ATOMIC_ACQUIRE, "agent");

    f32x4 c = *reinterpret_cast<const f32x4*>(&col_ws[b * K + j0]);
    f32x4 rsum = (f32x4){0.f, 0.f, 0.f, 0.f};
#pragma unroll
    for (int pblk = 0; pblk < 16; ++pblk)
        rsum += *reinterpret_cast<const f32x4*>(
            &rowpart[((size_t)(b * 16 + pblk)) * K + j0]);

    const float bc = b_col_p[0];
    const float br = b_row_p[0];
    float acc = (c.x + bc) * (rsum.x + br)
              + (c.y + bc) * (rsum.y + br)
              + (c.z + bc) * (rsum.z + br)
              + (c.w + bc) * (rsum.w + br);
#pragma unroll
    for (int off = 32; off; off >>= 1) acc += __shfl_xor(acc, off);

    __shared__ float red[4];
    if (lane == 0) red[wave] = acc;
    __syncthreads();
    const float S = red[0] + red[1] + red[2] + red[3];

    f32x4 o = (f32x4){S, S, S, S};
    *reinterpret_cast<f32x4*>(&out[b * K + j0]) = o;
}

extern "C" void kernel_launch(void* const* d_in, const int* in_sizes, int n_in,
                              void* d_out, int out_size, void* d_ws, size_t ws_size,
                              hipStream_t stream) {
    const float* x     = (const float*)d_in[0];
    const float* w_col = (const float*)d_in[1];
    const float* b_col = (const float*)d_in[2];
    const float* w_row = (const float*)d_in[3];
    const float* b_row = (const float*)d_in[4];
    float* out = (float*)d_out;

    float* col_ws   = (float*)d_ws;                            // NB*K floats
    float* rowpart  = col_ws + (size_t)NB * K;                 // NB*16*K floats
    int*   counters = (int*)(rowpart + (size_t)NB * 16 * K);   // NB ints

    hipMemsetAsync(counters, 0, NB * sizeof(int), stream);
    fused_kernel<<<NB * 16, 256, 0, stream>>>(x, w_col, w_row, b_col, b_row,
                                              out, col_ws, rowpart, counters);
}

// Round 11
// 99.391 us; speedup vs baseline: 1.2212x; 1.2212x over previous
//
#include <hip/hip_runtime.h>
#include <hip/hip_bf16.h>

// Output[b,0,i] = S[b] for all i, where
//   S[b] = sum_j (row[b,j] + b_row) * (col[b,j] + b_col)
//   col[b,i] = sum_j x[b,i,j] * w_col[j]   (weighted row-dot)
//   row[b,j] = sum_i x[b,i,j] * w_row[i]   (weighted column-sum)
//
// R11 = exact revert to R9 (best: 99.0 us).
// Ledger: NT loads +8us (R7 A/B). Depth-2 pipeline, uncapped (R8/R9).
// VGPR cap refuted (R5/R6: spills). Fusion refuted twice (R4: per-block
// wbl2 storm; R10: uncached scalar write-through = RMW traffic).
// Two-kernel structure is optimal: kernel boundary is the cheapest
// cross-XCD visibility mechanism for the 8.9 MB partial combine.

#define K 1024
#define NB 128

typedef float f32x4 __attribute__((ext_vector_type(4)));

__global__ __launch_bounds__(256) void
rowcol_kernel(const float* __restrict__ x,
              const float* __restrict__ w_col,
              const float* __restrict__ w_row,
              float* __restrict__ col_ws,     // [NB][K] raw (no bias)
              float* __restrict__ rowpart)    // [NB*16][K] per-block partials
{
    const int bid  = blockIdx.x;
    const int b    = bid >> 4;
    const int rb   = bid & 15;
    const int row0 = rb * 64;
    const int tid  = threadIdx.x;
    const int wave = tid >> 6;
    const int lane = tid & 63;

    const float* xb = x + (size_t)b * K * K;

    // Wave-uniform row base in SGPR so w_row[] reads scalarize to s_load.
    const int rbu = __builtin_amdgcn_readfirstlane(row0 + wave * 16);

    // Register-cache this lane's w_col fragment (reused by all 16 rows)
    f32x4 wc[4];
#pragma unroll
    for (int jt = 0; jt < 4; ++jt)
        wc[jt] = *reinterpret_cast<const f32x4*>(w_col + jt * 256 + lane * 4);

    // Per-lane column partials for row[b,j] (this wave's 16 rows)
    f32x4 p[4];
#pragma unroll
    for (int jt = 0; jt < 4; ++jt) p[jt] = (f32x4){0.f, 0.f, 0.f, 0.f};

    float cacc[16];

    // ---- depth-2 software-pipelined NT streaming loop ----
    // buf[0] holds even rows, buf[1] odd rows; k&1 static under full unroll.
    f32x4 buf[2][4];
    {
        const float* xr0 = xb + (size_t)rbu * K + lane * 4;
        const float* xr1 = xb + (size_t)(rbu + 1) * K + lane * 4;
#pragma unroll
        for (int jt = 0; jt < 4; ++jt)
            buf[0][jt] = __builtin_nontemporal_load(
                reinterpret_cast<const f32x4*>(xr0 + jt * 256));
#pragma unroll
        for (int jt = 0; jt < 4; ++jt)
            buf[1][jt] = __builtin_nontemporal_load(
                reinterpret_cast<const f32x4*>(xr1 + jt * 256));
    }

#pragma unroll
    for (int k = 0; k < 16; ++k) {
        f32x4 n0, n1, n2, n3;
        if (k < 14) {   // issue row k+2's loads before consuming row k
            const float* xn = xb + (size_t)(rbu + k + 2) * K + lane * 4;
            n0 = __builtin_nontemporal_load(reinterpret_cast<const f32x4*>(xn +   0));
            n1 = __builtin_nontemporal_load(reinterpret_cast<const f32x4*>(xn + 256));
            n2 = __builtin_nontemporal_load(reinterpret_cast<const f32x4*>(xn + 512));
            n3 = __builtin_nontemporal_load(reinterpret_cast<const f32x4*>(xn + 768));
        }
        const float wr = w_row[rbu + k];            // s_load, wave-uniform
        f32x4 a0 = buf[k & 1][0], a1 = buf[k & 1][1];
        f32x4 a2 = buf[k & 1][2], a3 = buf[k & 1][3];
        f32x4 c4;
        c4  = a0 * wc[0];
        c4 += a1 * wc[1];
        c4 += a2 * wc[2];
        c4 += a3 * wc[3];
        p[0] += a0 * wr;
        p[1] += a1 * wr;
        p[2] += a2 * wr;
        p[3] += a3 * wr;
        cacc[k] = (c4.x + c4.y) + (c4.z + c4.w);
        if (k < 14) {
            buf[k & 1][0] = n0; buf[k & 1][1] = n1;
            buf[k & 1][2] = n2; buf[k & 1][3] = n3;
        }
    }

    // Multiplexed butterfly: 16 row-dots reduced across 64 lanes.
#pragma unroll
    for (int lvl = 0; lvl < 4; ++lvl) {
        const int s = 1 << lvl;
        const int n = 16 >> (lvl + 1);
#pragma unroll
        for (int m = 0; m < n; ++m) {
            float a  = cacc[2 * m]     + __shfl_xor(cacc[2 * m],     s);
            float bb = cacc[2 * m + 1] + __shfl_xor(cacc[2 * m + 1], s);
            cacc[m] = (lane & s) ? bb : a;
        }
    }
    float r = cacc[0];
    r += __shfl_xor(r, 16);
    r += __shfl_xor(r, 32);
    if (lane < 16) col_ws[b * K + rbu + lane] = r;   // one coalesced 64B store

    // Combine the 4 waves' column partials in LDS, write this block's partial
    __shared__ float rp[4][K];   // 16 KiB
#pragma unroll
    for (int jt = 0; jt < 4; ++jt)
        *reinterpret_cast<f32x4*>(&rp[wave][jt * 256 + lane * 4]) = p[jt];
    __syncthreads();

    const int j0 = tid * 4;   // thread tid owns columns j0..j0+3
    f32x4 s0 = *reinterpret_cast<const f32x4*>(&rp[0][j0]);
    f32x4 s1 = *reinterpret_cast<const f32x4*>(&rp[1][j0]);
    f32x4 s2 = *reinterpret_cast<const f32x4*>(&rp[2][j0]);
    f32x4 s3 = *reinterpret_cast<const f32x4*>(&rp[3][j0]);
    f32x4 s = (s0 + s1) + (s2 + s3);
    *reinterpret_cast<f32x4*>(&rowpart[(size_t)bid * K + j0]) = s;
}

__global__ __launch_bounds__(256) void
finalize_kernel(const float* __restrict__ col_ws,
                const float* __restrict__ rowpart,
                const float* __restrict__ b_col_p,
                const float* __restrict__ b_row_p,
                float* __restrict__ out)
{
    const int b    = blockIdx.x;
    const int tid  = threadIdx.x;
    const int wave = tid >> 6;
    const int lane = tid & 63;
    const float bc = b_col_p[0];
    const float br = b_row_p[0];

    const int j0 = tid * 4;
    f32x4 c = *reinterpret_cast<const f32x4*>(&col_ws[b * K + j0]);
    f32x4 r = (f32x4){0.f, 0.f, 0.f, 0.f};
#pragma unroll
    for (int pblk = 0; pblk < 16; ++pblk)
        r += *reinterpret_cast<const f32x4*>(
            &rowpart[((size_t)(b * 16 + pblk)) * K + j0]);

    float acc = (c.x + bc) * (r.x + br)
              + (c.y + bc) * (r.y + br)
              + (c.z + bc) * (r.z + br)
              + (c.w + bc) * (r.w + br);
#pragma unroll
    for (int off = 32; off; off >>= 1) acc += __shfl_xor(acc, off);

    __shared__ float red[4];
    if (lane == 0) red[wave] = acc;
    __syncthreads();
    const float S = red[0] + red[1] + red[2] + red[3];

    f32x4 o = (f32x4){S, S, S, S};
    *reinterpret_cast<f32x4*>(&out[b * K + j0]) = o;
}

extern "C" void kernel_launch(void* const* d_in, const int* in_sizes, int n_in,
                              void* d_out, int out_size, void* d_ws, size_t ws_size,
                              hipStream_t stream) {
    const float* x     = (const float*)d_in[0];
    const float* w_col = (const float*)d_in[1];
    const float* b_col = (const float*)d_in[2];
    const float* w_row = (const float*)d_in[3];
    const float* b_row = (const float*)d_in[4];
    float* out = (float*)d_out;

    float* col_ws  = (float*)d_ws;               // NB*K floats
    float* rowpart = col_ws + (size_t)NB * K;    // NB*16*K floats

    rowcol_kernel<<<NB * 16, 256, 0, stream>>>(x, w_col, w_row, col_ws, rowpart);
    finalize_kernel<<<NB, 256, 0, stream>>>(col_ws, rowpart, b_col, b_row, out);
}